// Round 6
// baseline (2609.700 us; speedup 1.0000x reference)
//
#include <hip/hip_runtime.h>

// Problem constants (fixed by the reference)
#define BB    8
#define NN    8192
#define MM    2048
#define CFEAT 64
#define OUTC  128
#define NS    32
#define NBUCK 128     // buckets per batch
#define BSZ   64      // points per bucket

// ---------------------------------------------------------------------------
// DPP wave64 reductions (row_shr 1/2/4/8 + bcast15 + bcast31; lane63 = full
// reduction; readlane(63) broadcasts). bound_ctrl=false + old=self => invalid
// lanes contribute identity.
// ---------------------------------------------------------------------------
template<int C, int R>
__device__ __forceinline__ float dpp_maxf(float v) {
    int t = __builtin_amdgcn_update_dpp(__float_as_int(v), __float_as_int(v), C, R, 0xf, false);
    return fmaxf(v, __int_as_float(t));
}
template<int C, int R>
__device__ __forceinline__ float dpp_minf(float v) {
    int t = __builtin_amdgcn_update_dpp(__float_as_int(v), __float_as_int(v), C, R, 0xf, false);
    return fminf(v, __int_as_float(t));
}
template<int C, int R>
__device__ __forceinline__ unsigned long long dpp_maxu64(unsigned long long v) {
    unsigned lo = (unsigned)v, hi = (unsigned)(v >> 32);
    unsigned tlo = (unsigned)__builtin_amdgcn_update_dpp((int)lo, (int)lo, C, R, 0xf, false);
    unsigned thi = (unsigned)__builtin_amdgcn_update_dpp((int)hi, (int)hi, C, R, 0xf, false);
    unsigned long long t = ((unsigned long long)thi << 32) | tlo;
    return t > v ? t : v;
}
__device__ __forceinline__ float wred_maxf(float v) {
    v = dpp_maxf<0x111,0xf>(v); v = dpp_maxf<0x112,0xf>(v);
    v = dpp_maxf<0x114,0xf>(v); v = dpp_maxf<0x118,0xf>(v);
    v = dpp_maxf<0x142,0xa>(v); v = dpp_maxf<0x143,0xc>(v);
    return __int_as_float(__builtin_amdgcn_readlane(__float_as_int(v), 63));
}
__device__ __forceinline__ float wred_minf(float v) {
    v = dpp_minf<0x111,0xf>(v); v = dpp_minf<0x112,0xf>(v);
    v = dpp_minf<0x114,0xf>(v); v = dpp_minf<0x118,0xf>(v);
    v = dpp_minf<0x142,0xa>(v); v = dpp_minf<0x143,0xc>(v);
    return __int_as_float(__builtin_amdgcn_readlane(__float_as_int(v), 63));
}
__device__ __forceinline__ unsigned long long wred_maxu64(unsigned long long v) {
    v = dpp_maxu64<0x111,0xf>(v); v = dpp_maxu64<0x112,0xf>(v);
    v = dpp_maxu64<0x114,0xf>(v); v = dpp_maxu64<0x118,0xf>(v);
    v = dpp_maxu64<0x142,0xa>(v); v = dpp_maxu64<0x143,0xc>(v);
    unsigned lo = (unsigned)__builtin_amdgcn_readlane((int)(unsigned)v, 63);
    unsigned hi = (unsigned)__builtin_amdgcn_readlane((int)(unsigned)(v >> 32), 63);
    return ((unsigned long long)hi << 32) | lo;
}

// identical fma shape for point distance and bbox lower bound => lb2 <= d2
// holds in f32 by per-op monotonicity (safe exact skipping).
__device__ __forceinline__ float distsq(float dx, float dy, float dz) {
    return fmaf(dz, dz, fmaf(dy, dy, dx * dx));
}

// key layout: (dmin_bits << 32) | ((8191-orig) << 13) | pos
// u64 max  =>  max dmin, ties -> min orig (orig unique => total order).
__device__ __forceinline__ unsigned long long pack_key(float dmn, unsigned orig, unsigned pos) {
    return ((unsigned long long)__float_as_uint(dmn) << 32)
         | ((unsigned long long)(8191u - orig) << 13) | pos;
}

// ---------------------------------------------------------------------------
// Fused kernel, 64-thread blocks, 144KB dynamic LDS:
//   blocks 0..7    : bucketed FPS, one wave per batch, zero barriers
//   blocks 8..263  : feat*W precompute (G), 256 points each, concurrent
// FPS LDS: sx,sy,sz,sdmin [8192]*4 = 131072 B; sorig u16[8192] = 16384 B.
// bbox + bucket keys live in REGISTERS (lane L owns buckets L and L+64).
// ---------------------------------------------------------------------------
#define FPS_LDS_BYTES 147456

__global__ void fps_featw_kernel(
    const float* __restrict__ xyz, const int* __restrict__ key_mask,
    const float* __restrict__ feat, const float* __restrict__ W,
    int* __restrict__ fps_idx, float* __restrict__ G)
{
    extern __shared__ float sm[];
    const int lane = threadIdx.x;   // 0..63

    if (blockIdx.x >= BB) {
        // ---------------- featW path: G[p][o] = feat[p][:64] . W[o][:64] -----
        float* Wt = sm;   // [c][o], 32 KB
        for (int i = lane; i < CFEAT * OUTC; i += 64) {
            int c = i >> 7, o = i & 127;
            Wt[i] = W[o * 67 + c];
        }
        __syncthreads();
        const int p0 = (blockIdx.x - BB) * 256;
        for (int k = 0; k < 256; k += 2) {
            int pA = p0 + k, pB = pA + 1;
            float fa = feat[(size_t)pA * CFEAT + lane];
            float fb = feat[(size_t)pB * CFEAT + lane];
            float a0 = 0.f, a1 = 0.f, b0 = 0.f, b1 = 0.f;
            #pragma unroll 8
            for (int c = 0; c < CFEAT; ++c) {
                float ca = __shfl(fa, c), cb = __shfl(fb, c);
                float w0 = Wt[c * OUTC + lane], w1 = Wt[c * OUTC + 64 + lane];
                a0 = fmaf(ca, w0, a0); a1 = fmaf(ca, w1, a1);
                b0 = fmaf(cb, w0, b0); b1 = fmaf(cb, w1, b1);
            }
            G[(size_t)pA * OUTC + lane]      = a0;
            G[(size_t)pA * OUTC + 64 + lane] = a1;
            G[(size_t)pB * OUTC + lane]      = b0;
            G[(size_t)pB * OUTC + 64 + lane] = b1;
        }
        return;
    }

    // ---------------- FPS path ----------------
    float*          sx    = sm;                       // [8192]
    float*          sy    = sx + NN;
    float*          sz    = sy + NN;
    float*          sdmin = sz + NN;
    unsigned short* sorig = (unsigned short*)(sdmin + NN); // [8192]

    const int b = blockIdx.x;

    // pass A: count masked points
    int nm_total = 0;
    for (int c = 0; c < 128; ++c) {
        int km = key_mask[b * NN + c * 64 + lane];
        nm_total += (int)__popcll(__ballot(km != 0));
    }
    const int NU = NN - nm_total;   // masked points go to positions [NU, NN)

    // pass B: stable partition (unmasked by idx, then masked by idx) + scale
    int nu_seen = 0, nm_seen = 0;
    for (int c = 0; c < 128; ++c) {
        int orig = c * 64 + lane;
        const float* p = xyz + ((size_t)b * NN + orig) * 3;
        float x = p[0], y = p[1], z = p[2];
        int km = key_mask[b * NN + orig];
        float off = km ? ((float)orig + 10.0f) * 10.0f : 0.0f;  // exact
        unsigned long long bm = __ballot(km != 0);
        int below = (int)__popcll(bm & ((1ull << lane) - 1ull));
        int pos = km ? (NU + nm_seen + below) : (nu_seen + (lane - below));
        sx[pos] = x + off; sy[pos] = y + off; sz[pos] = z + off;
        sdmin[pos] = 1e10f;
        sorig[pos] = (unsigned short)orig;
        int cm = (int)__popcll(bm);
        nm_seen += cm; nu_seen += 64 - cm;
    }

    // pass C: per-bucket bbox + initial key -> owner lane's REGISTERS
    float lox0, loy0, loz0, hix0, hiy0, hiz0;
    float lox1, loy1, loz1, hix1, hiy1, hiz1;
    unsigned long long key0 = 0, key1 = 0;
    for (int j = 0; j < NBUCK; ++j) {
        int p = (j << 6) + lane;
        float x = sx[p], y = sy[p], z = sz[p];
        float lx = wred_minf(x), hx = wred_maxf(x);
        float ly = wred_minf(y), hy = wred_maxf(y);
        float lz = wred_minf(z), hz = wred_maxf(z);
        unsigned long long k0 = wred_maxu64(pack_key(1e10f, sorig[p], (unsigned)p));
        if (lane == (j & 63)) {
            if (j < 64) { lox0=lx; hix0=hx; loy0=ly; hiy0=hy; loz0=lz; hiz0=hz; key0=k0; }
            else        { lox1=lx; hix1=hx; loy1=ly; hiy1=hy; loz1=lz; hiz1=hz; key1=k0; }
        }
    }

    // main loop: 2048 selections, zero barriers (single wave)
    int km0 = key_mask[b * NN];
    int pos0 = km0 ? NU : 0;                 // position of orig index 0
    float qx = sx[pos0], qy = sy[pos0], qz = sz[pos0];
    int s_last = 0;

    for (int it = 0; it < MM; ++it) {
        if (lane == 0) fps_idx[b * MM + it] = s_last;

        // phase 1: skip tests, all-register (lane owns buckets lane, lane+64)
        float dmax0 = __uint_as_float((unsigned)(key0 >> 32));
        float dmax1 = __uint_as_float((unsigned)(key1 >> 32));
        float dx0 = fmaxf(fmaxf(lox0 - qx, qx - hix0), 0.f);
        float dy0 = fmaxf(fmaxf(loy0 - qy, qy - hiy0), 0.f);
        float dz0 = fmaxf(fmaxf(loz0 - qz, qz - hiz0), 0.f);
        float lb0 = distsq(dx0, dy0, dz0);
        float dx1 = fmaxf(fmaxf(lox1 - qx, qx - hix1), 0.f);
        float dy1 = fmaxf(fmaxf(loy1 - qy, qy - hiy1), 0.f);
        float dz1 = fmaxf(fmaxf(loz1 - qz, qz - hiz1), 0.f);
        float lb1 = distsq(dx1, dy1, dz1);
        unsigned long long m0 = __ballot(lb0 < dmax0);
        unsigned long long m1 = __ballot(lb1 < dmax1);

        // phase 2: update pending buckets, 4 at a time (pad w/ duplicates --
        // idempotent: reads precede writes, same q => same values)
        while (m0 | m1) {
            int ja, jb, jc, jd;
            { if (m0) { ja = __ffsll(m0) - 1;      m0 &= m0 - 1; }
              else    { ja = 64 + __ffsll(m1) - 1; m1 &= m1 - 1; } }
            if (m0)      { jb = __ffsll(m0) - 1;      m0 &= m0 - 1; }
            else if (m1) { jb = 64 + __ffsll(m1) - 1; m1 &= m1 - 1; }
            else jb = ja;
            if (m0)      { jc = __ffsll(m0) - 1;      m0 &= m0 - 1; }
            else if (m1) { jc = 64 + __ffsll(m1) - 1; m1 &= m1 - 1; }
            else jc = ja;
            if (m0)      { jd = __ffsll(m0) - 1;      m0 &= m0 - 1; }
            else if (m1) { jd = 64 + __ffsll(m1) - 1; m1 &= m1 - 1; }
            else jd = ja;

            const int pa = (ja << 6) + lane, pb = (jb << 6) + lane;
            const int pc = (jc << 6) + lane, pd = (jd << 6) + lane;
            // issue all LDS reads up front
            float xa = sx[pa], ya = sy[pa], za = sz[pa], oa_d = sdmin[pa];
            float xb = sx[pb], yb = sy[pb], zb = sz[pb], ob_d = sdmin[pb];
            float xc = sx[pc], yc = sy[pc], zc = sz[pc], oc_d = sdmin[pc];
            float xd = sx[pd], yd = sy[pd], zd = sz[pd], od_d = sdmin[pd];
            unsigned oga = sorig[pa], ogb = sorig[pb], ogc = sorig[pc], ogd = sorig[pd];

            float na = fminf(oa_d, distsq(xa - qx, ya - qy, za - qz));
            float nb = fminf(ob_d, distsq(xb - qx, yb - qy, zb - qz));
            float nc = fminf(oc_d, distsq(xc - qx, yc - qy, zc - qz));
            float nd = fminf(od_d, distsq(xd - qx, yd - qy, zd - qz));
            sdmin[pa] = na; sdmin[pb] = nb; sdmin[pc] = nc; sdmin[pd] = nd;

            unsigned long long ka = pack_key(na, oga, (unsigned)pa);
            unsigned long long kb = pack_key(nb, ogb, (unsigned)pb);
            unsigned long long kc = pack_key(nc, ogc, (unsigned)pc);
            unsigned long long kd = pack_key(nd, ogd, (unsigned)pd);
            // 4 interleaved u64-max DPP chains (ILP hides chain latency)
            #define RSTEP(C,R) \
                ka = dpp_maxu64<C,R>(ka); kb = dpp_maxu64<C,R>(kb); \
                kc = dpp_maxu64<C,R>(kc); kd = dpp_maxu64<C,R>(kd);
            RSTEP(0x111,0xf) RSTEP(0x112,0xf) RSTEP(0x114,0xf)
            RSTEP(0x118,0xf) RSTEP(0x142,0xa) RSTEP(0x143,0xc)
            #undef RSTEP
            {   unsigned lo, hi;
                lo = (unsigned)__builtin_amdgcn_readlane((int)(unsigned)ka, 63);
                hi = (unsigned)__builtin_amdgcn_readlane((int)(unsigned)(ka >> 32), 63);
                ka = ((unsigned long long)hi << 32) | lo;
                lo = (unsigned)__builtin_amdgcn_readlane((int)(unsigned)kb, 63);
                hi = (unsigned)__builtin_amdgcn_readlane((int)(unsigned)(kb >> 32), 63);
                kb = ((unsigned long long)hi << 32) | lo;
                lo = (unsigned)__builtin_amdgcn_readlane((int)(unsigned)kc, 63);
                hi = (unsigned)__builtin_amdgcn_readlane((int)(unsigned)(kc >> 32), 63);
                kc = ((unsigned long long)hi << 32) | lo;
                lo = (unsigned)__builtin_amdgcn_readlane((int)(unsigned)kd, 63);
                hi = (unsigned)__builtin_amdgcn_readlane((int)(unsigned)(kd >> 32), 63);
                kd = ((unsigned long long)hi << 32) | lo;
            }
            // owner-lane register updates (duplicates write identical values)
            if (lane == (ja & 63)) { if (ja < 64) key0 = ka; else key1 = ka; }
            if (lane == (jb & 63)) { if (jb < 64) key0 = kb; else key1 = kb; }
            if (lane == (jc & 63)) { if (jc < 64) key0 = kc; else key1 = kc; }
            if (lane == (jd & 63)) { if (jd < 64) key0 = kd; else key1 = kd; }
        }

        // phase 3: global argmax = one u64 chain over the 128 register keys
        unsigned long long kk = key0 > key1 ? key0 : key1;
        kk = wred_maxu64(kk);
        s_last = 8191 - (int)((kk >> 13) & 8191u);
        int pos = (int)(kk & 8191u);
        qx = sx[pos]; qy = sy[pos]; qz = sz[pos];
    }
}

// ---------------------------------------------------------------------------
// K3: fused ball query + gather + (G + gxyz*Wxyz + b) + LeakyReLU + pool.
// ---------------------------------------------------------------------------
__global__ __launch_bounds__(256) void group_kernel(
    const float* __restrict__ xyz, const int* __restrict__ mask,
    const int* __restrict__ key_mask, const float* __restrict__ W,
    const float* __restrict__ bias, const int* __restrict__ fps_idx,
    const float* __restrict__ G, float* __restrict__ out)
{
    __shared__ int s_idx[4][NS];
    const int t = threadIdx.x, lane = t & 63, w = t >> 6;
    const int q = blockIdx.x * 4 + w;         // 0..16383
    const int b = q >> 11;
    const int gi = fps_idx[q];

    const float* xb = xyz + (size_t)b * NN * 3;
    const float* qp = xb + (size_t)gi * 3;
    const float qx = qp[0], qy = qp[1], qz = qp[2];

    float* out0 = out;
    float* onx  = out  + (size_t)BB * MM * OUTC;
    float* onm  = onx  + (size_t)BB * MM * 3;
    float* onk  = onm  + (size_t)BB * MM;
    if (lane == 0) {
        onx[(size_t)q * 3 + 0] = qx;
        onx[(size_t)q * 3 + 1] = qy;
        onx[(size_t)q * 3 + 2] = qz;
        onm[q] = (float)mask[b * NN + gi];
        onk[q] = (float)key_mask[b * NN + gi];
    }

    const float q2 = qx * qx + qy * qy + qz * qz;
    int have = 0, idx0 = -1;
    for (int base = 0; base < NN; base += 64) {
        int n = base + lane;
        const float* p = xb + n * 3;
        float x = p[0], y = p[1], z = p[2];
        float p2 = x * x + y * y + z * z;
        float dt = qx * x + qy * y + qz * z;
        float d2 = (q2 + p2) - 2.0f * dt;
        bool within = d2 < 0.25f;
        unsigned long long bm = __ballot(within);
        if (bm) {
            if (idx0 < 0) idx0 = base + (__ffsll(bm) - 1);
            if (within) {
                int pos = have + __popcll(bm & ((1ull << lane) - 1ull));
                if (pos < NS) s_idx[w][pos] = n;
            }
            have += (int)__popcll(bm);
            if (have >= NS) break;
        }
    }
    if (have > NS) have = NS;
    if (lane >= have && lane < NS) s_idx[w][lane] = idx0;   // pad with first valid
    __asm__ volatile("s_waitcnt lgkmcnt(0)" ::: "memory");  // LDS writes visible

    const float w0x = W[lane * 67 + 64], w0y = W[lane * 67 + 65], w0z = W[lane * 67 + 66];
    const float w1x = W[(lane + 64) * 67 + 64], w1y = W[(lane + 64) * 67 + 65], w1z = W[(lane + 64) * 67 + 66];
    const float b0 = bias[lane], b1 = bias[lane + 64];
    const float* Gb = G + (size_t)b * NN * OUTC;

    float acc = 0.f, mx = -3.4e38f;
    #pragma unroll 4
    for (int s = 0; s < NS; ++s) {
        int id = s_idx[w][s];
        const float* pr = xb + (size_t)id * 3;
        float dx = pr[0] - qx, dy = pr[1] - qy, dz = pr[2] - qz;
        const float* g = Gb + (size_t)id * OUTC;
        float y0 = g[lane]      + dx * w0x + dy * w0y + dz * w0z + b0;
        float y1 = g[lane + 64] + dx * w1x + dy * w1y + dz * w1z + b1;
        y0 = y0 > 0.f ? y0 : 0.01f * y0;
        y1 = y1 > 0.f ? y1 : 0.01f * y1;
        acc += y0;
        mx = fmaxf(mx, y1);
    }
    out0[(size_t)q * OUTC + lane]      = acc * (1.0f / 32.0f);
    out0[(size_t)q * OUTC + 64 + lane] = mx;
}

// ---------------------------------------------------------------------------
extern "C" void kernel_launch(void* const* d_in, const int* in_sizes, int n_in,
                              void* d_out, int out_size, void* d_ws, size_t ws_size,
                              hipStream_t stream)
{
    const float* feat  = (const float*)d_in[0];
    const float* xyz   = (const float*)d_in[1];
    const int*   mask  = (const int*)d_in[2];
    const int*   kmask = (const int*)d_in[3];
    const float* W     = (const float*)d_in[4];
    const float* bias  = (const float*)d_in[5];
    float* out = (float*)d_out;

    int*   fps_idx = (int*)d_ws;                          // 64 KB
    float* G       = (float*)((char*)d_ws + 65536);       // 32 MB

    // opt-in to >64KB dynamic LDS (host-side setting; graph-capture safe)
    hipFuncSetAttribute((const void*)fps_featw_kernel,
                        hipFuncAttributeMaxDynamicSharedMemorySize, FPS_LDS_BYTES);

    hipLaunchKernelGGL(fps_featw_kernel, dim3(BB + 256), dim3(64), FPS_LDS_BYTES, stream,
                       xyz, kmask, feat, W, fps_idx, G);
    hipLaunchKernelGGL(group_kernel, dim3(4096), dim3(256), 0, stream,
                       xyz, mask, kmask, W, bias, fps_idx, G, out);
}

// Round 7
// 1731.173 us; speedup vs baseline: 1.5075x; 1.5075x over previous
//
#include <hip/hip_runtime.h>

// Problem constants (fixed by the reference)
#define BB    8
#define NN    8192
#define MM    2048
#define CFEAT 64
#define OUTC  128
#define NS    32
#define NBUCK 128     // buckets per batch
#define FPS_T 512     // 8 waves; bucket j owned by wave (j & 7)

// ---------------------------------------------------------------------------
// DPP wave64 reductions (row_shr 1/2/4/8 + bcast15 + bcast31; lane63 holds the
// full reduction). bound_ctrl=false + old=self => shifted-out lanes = identity.
// ---------------------------------------------------------------------------
template<int C, int R>
__device__ __forceinline__ float dpp_maxf(float v) {
    int t = __builtin_amdgcn_update_dpp(__float_as_int(v), __float_as_int(v), C, R, 0xf, false);
    return fmaxf(v, __int_as_float(t));
}
template<int C, int R>
__device__ __forceinline__ float dpp_minf(float v) {
    int t = __builtin_amdgcn_update_dpp(__float_as_int(v), __float_as_int(v), C, R, 0xf, false);
    return fminf(v, __int_as_float(t));
}
template<int C, int R>
__device__ __forceinline__ unsigned long long dpp_maxu64(unsigned long long v) {
    unsigned lo = (unsigned)v, hi = (unsigned)(v >> 32);
    unsigned tlo = (unsigned)__builtin_amdgcn_update_dpp((int)lo, (int)lo, C, R, 0xf, false);
    unsigned thi = (unsigned)__builtin_amdgcn_update_dpp((int)hi, (int)hi, C, R, 0xf, false);
    unsigned long long t = ((unsigned long long)thi << 32) | tlo;
    return t > v ? t : v;
}
__device__ __forceinline__ float wred_maxf(float v) {
    v = dpp_maxf<0x111,0xf>(v); v = dpp_maxf<0x112,0xf>(v);
    v = dpp_maxf<0x114,0xf>(v); v = dpp_maxf<0x118,0xf>(v);
    v = dpp_maxf<0x142,0xa>(v); v = dpp_maxf<0x143,0xc>(v);
    return __int_as_float(__builtin_amdgcn_readlane(__float_as_int(v), 63));
}
__device__ __forceinline__ float wred_minf(float v) {
    v = dpp_minf<0x111,0xf>(v); v = dpp_minf<0x112,0xf>(v);
    v = dpp_minf<0x114,0xf>(v); v = dpp_minf<0x118,0xf>(v);
    v = dpp_minf<0x142,0xa>(v); v = dpp_minf<0x143,0xc>(v);
    return __int_as_float(__builtin_amdgcn_readlane(__float_as_int(v), 63));
}
// chain only: lane 63 holds the max (no broadcast)
__device__ __forceinline__ unsigned long long chain_maxu64(unsigned long long v) {
    v = dpp_maxu64<0x111,0xf>(v); v = dpp_maxu64<0x112,0xf>(v);
    v = dpp_maxu64<0x114,0xf>(v); v = dpp_maxu64<0x118,0xf>(v);
    v = dpp_maxu64<0x142,0xa>(v); v = dpp_maxu64<0x143,0xc>(v);
    return v;
}

// identical fma shape for point distance and bbox lower bound => lb2 <= d2
// holds in f32 by per-op monotonicity (safe exact skipping).
__device__ __forceinline__ float distsq(float dx, float dy, float dz) {
    return fmaf(dz, dz, fmaf(dy, dy, dx * dx));
}

// key layout: (dmin_bits << 32) | ((8191-orig) << 13) | pos
// u64 max  =>  max dmin, ties -> min orig (orig unique => total order).
// Validated bit-exact in R6 (passed correctness with this packing).
__device__ __forceinline__ unsigned long long pack_key(float dmn, unsigned orig, unsigned pos) {
    return ((unsigned long long)__float_as_uint(dmn) << 32)
         | ((unsigned long long)(8191u - orig) << 13) | pos;
}

// ---------------------------------------------------------------------------
// LDS layout (byte offsets), FPS path:
//   sx      [8192] f32       0
//   sy      [8192] f32   32768
//   sz      [8192] f32   65536
//   sdmin   [8192] f32   98304
//   sorig   [8192] u16  131072
//   skey    [128]  u64  147456   (hi word = bucket dmax bits)
//   bbox 6x [128]  f32  148480
//   s_misc  [4]    i32  151552
// total 151568 -> alloc 152064 (<= 160KB/CU, 1 block/CU)
// ---------------------------------------------------------------------------
#define FPS_LDS_BYTES 152064

__global__ __launch_bounds__(FPS_T) void fps_featw_kernel(
    const float* __restrict__ xyz, const int* __restrict__ key_mask,
    const float* __restrict__ feat, const float* __restrict__ W,
    int* __restrict__ fps_idx, float* __restrict__ G)
{
    extern __shared__ float sm[];
    const int t    = threadIdx.x;
    const int lane = t & 63;
    const int w    = t >> 6;

    if (blockIdx.x >= BB) {
        // ------- featW path: 32 blocks x 8 waves x 256 pts -------
        float* Wt = sm;   // [c][o], 32 KB
        for (int i = t; i < CFEAT * OUTC; i += FPS_T) {
            int c = i >> 7, o = i & 127;
            Wt[i] = W[o * 67 + c];
        }
        __syncthreads();
        const int p0 = (blockIdx.x - BB) * 2048 + w * 256;
        for (int k = 0; k < 256; k += 2) {
            int pA = p0 + k, pB = pA + 1;
            float fa = feat[(size_t)pA * CFEAT + lane];
            float fb = feat[(size_t)pB * CFEAT + lane];
            float a0 = 0.f, a1 = 0.f, b0 = 0.f, b1 = 0.f;
            #pragma unroll 8
            for (int c = 0; c < CFEAT; ++c) {
                float ca = __shfl(fa, c), cb = __shfl(fb, c);
                float w0 = Wt[c * OUTC + lane], w1 = Wt[c * OUTC + 64 + lane];
                a0 = fmaf(ca, w0, a0); a1 = fmaf(ca, w1, a1);
                b0 = fmaf(cb, w0, b0); b1 = fmaf(cb, w1, b1);
            }
            G[(size_t)pA * OUTC + lane]      = a0;
            G[(size_t)pA * OUTC + 64 + lane] = a1;
            G[(size_t)pB * OUTC + lane]      = b0;
            G[(size_t)pB * OUTC + 64 + lane] = b1;
        }
        return;
    }

    // ------- FPS path -------
    float*              sx    = sm;
    float*              sy    = sx + NN;
    float*              sz    = sy + NN;
    float*              sdmin = sz + NN;
    unsigned short*     sorig = (unsigned short*)(sdmin + NN);
    unsigned long long* skey  = (unsigned long long*)((char*)sm + 147456);
    float*              blox  = (float*)((char*)sm + 148480);
    float*              bloy  = blox + NBUCK;
    float*              bloz  = bloy + NBUCK;
    float*              bhix  = bloz + NBUCK;
    float*              bhiy  = bhix + NBUCK;
    float*              bhiz  = bhiy + NBUCK;
    int*                s_misc = (int*)((char*)sm + 151552);

    const int b = blockIdx.x;

    if (w == 0) {
        // pass A: count masked points (wave 0 only)
        int nm_total = 0;
        for (int c = 0; c < 128; ++c) {
            int km = key_mask[b * NN + c * 64 + lane];
            nm_total += (int)__popcll(__ballot(km != 0));
        }
        const int NU0 = NN - nm_total;
        if (lane == 0) *s_misc = NU0;

        // pass B: stable partition (unmasked by idx, then masked by idx) + scale
        int nu_seen = 0, nm_seen = 0;
        for (int c = 0; c < 128; ++c) {
            int orig = c * 64 + lane;
            const float* p = xyz + ((size_t)b * NN + orig) * 3;
            float x = p[0], y = p[1], z = p[2];
            int km = key_mask[b * NN + orig];
            float off = km ? ((float)orig + 10.0f) * 10.0f : 0.0f;  // exact
            unsigned long long bm = __ballot(km != 0);
            int below = (int)__popcll(bm & ((1ull << lane) - 1ull));
            int pos = km ? (NU0 + nm_seen + below) : (nu_seen + (lane - below));
            sx[pos] = x + off; sy[pos] = y + off; sz[pos] = z + off;
            sdmin[pos] = 1e10f;
            sorig[pos] = (unsigned short)orig;
            int cm = (int)__popcll(bm);
            nm_seen += cm; nu_seen += 64 - cm;
        }
    }
    __syncthreads();
    const int NU = *s_misc;

    // pass C: per-bucket bbox + initial key, wave w handles its own buckets
    for (int i = 0; i < 16; ++i) {
        int j = (i << 3) | w;
        int p = (j << 6) + lane;
        float x = sx[p], y = sy[p], z = sz[p];
        float lx = wred_minf(x), hx = wred_maxf(x);
        float ly = wred_minf(y), hy = wred_maxf(y);
        float lz = wred_minf(z), hz = wred_maxf(z);
        unsigned long long k0 = chain_maxu64(pack_key(1e10f, sorig[p], (unsigned)p));
        if (lane == 0) {
            blox[j] = lx; bhix[j] = hx;
            bloy[j] = ly; bhiy[j] = hy;
            bloz[j] = lz; bhiz[j] = hz;
        }
        if (lane == 63) skey[j] = k0;
    }
    __syncthreads();

    // initial query = orig index 0
    int km0 = key_mask[b * NN];
    int pos0 = km0 ? NU : 0;
    float qx = sx[pos0], qy = sy[pos0], qz = sz[pos0];
    int s_last = 0;

    for (int it = 0; it < MM; ++it) {
        if (t == 0) fps_idx[b * MM + it] = s_last;

        // phase 1: skip tests on OWN buckets only (j = (i<<3)|w)
        int i15 = lane & 15;
        int j = (i15 << 3) | w;
        float dmax = __uint_as_float(((const unsigned*)(skey + j))[1]);
        float dx = fmaxf(fmaxf(blox[j] - qx, qx - bhix[j]), 0.f);
        float dy = fmaxf(fmaxf(bloy[j] - qy, qy - bhiy[j]), 0.f);
        float dz = fmaxf(fmaxf(bloz[j] - qz, qz - bhiz[j]), 0.f);
        float lb = distsq(dx, dy, dz);
        unsigned long long pend = __ballot(lb < dmax) & 0xFFFFull;

        // phase 2: update own pending buckets, one cooperative pass each
        while (pend) {
            int i = __ffsll(pend) - 1; pend &= pend - 1;
            int jj = (i << 3) | w;
            int p = (jj << 6) + lane;
            float d   = distsq(sx[p] - qx, sy[p] - qy, sz[p] - qz);
            float dmn = fminf(sdmin[p], d);
            sdmin[p] = dmn;
            unsigned long long k = chain_maxu64(pack_key(dmn, sorig[p], (unsigned)p));
            if (lane == 63) skey[jj] = k;
        }
        __syncthreads();   // B1: all skey updates visible

        // phase 3: global argmax over 128 keys (2/lane), redundant per wave
        unsigned long long k0 = skey[lane];
        unsigned long long k1 = skey[lane + 64];
        unsigned long long kk = chain_maxu64(k0 > k1 ? k0 : k1);
        unsigned lo = (unsigned)__builtin_amdgcn_readlane((int)(unsigned)kk, 63);
        unsigned hi = (unsigned)__builtin_amdgcn_readlane((int)(unsigned)(kk >> 32), 63);
        kk = ((unsigned long long)hi << 32) | lo;
        s_last = 8191 - (int)((kk >> 13) & 8191u);
        int pos = (int)(kk & 8191u);
        qx = sx[pos]; qy = sy[pos]; qz = sz[pos];
        __syncthreads();   // B2: phase-3 reads done before next iter's writes
    }
}

// ---------------------------------------------------------------------------
// K3: fused ball query + gather + (G + gxyz*Wxyz + b) + LeakyReLU + pool.
// ---------------------------------------------------------------------------
__global__ __launch_bounds__(256) void group_kernel(
    const float* __restrict__ xyz, const int* __restrict__ mask,
    const int* __restrict__ key_mask, const float* __restrict__ W,
    const float* __restrict__ bias, const int* __restrict__ fps_idx,
    const float* __restrict__ G, float* __restrict__ out)
{
    __shared__ int s_idx[4][NS];
    const int t = threadIdx.x, lane = t & 63, w = t >> 6;
    const int q = blockIdx.x * 4 + w;         // 0..16383
    const int b = q >> 11;
    const int gi = fps_idx[q];

    const float* xb = xyz + (size_t)b * NN * 3;
    const float* qp = xb + (size_t)gi * 3;
    const float qx = qp[0], qy = qp[1], qz = qp[2];

    float* out0 = out;
    float* onx  = out  + (size_t)BB * MM * OUTC;
    float* onm  = onx  + (size_t)BB * MM * 3;
    float* onk  = onm  + (size_t)BB * MM;
    if (lane == 0) {
        onx[(size_t)q * 3 + 0] = qx;
        onx[(size_t)q * 3 + 1] = qy;
        onx[(size_t)q * 3 + 2] = qz;
        onm[q] = (float)mask[b * NN + gi];
        onk[q] = (float)key_mask[b * NN + gi];
    }

    const float q2 = qx * qx + qy * qy + qz * qz;
    int have = 0, idx0 = -1;
    for (int base = 0; base < NN; base += 64) {
        int n = base + lane;
        const float* p = xb + n * 3;
        float x = p[0], y = p[1], z = p[2];
        float p2 = x * x + y * y + z * z;
        float dt = qx * x + qy * y + qz * z;
        float d2 = (q2 + p2) - 2.0f * dt;
        bool within = d2 < 0.25f;
        unsigned long long bm = __ballot(within);
        if (bm) {
            if (idx0 < 0) idx0 = base + (__ffsll(bm) - 1);
            if (within) {
                int pos = have + __popcll(bm & ((1ull << lane) - 1ull));
                if (pos < NS) s_idx[w][pos] = n;
            }
            have += (int)__popcll(bm);
            if (have >= NS) break;
        }
    }
    if (have > NS) have = NS;
    if (lane >= have && lane < NS) s_idx[w][lane] = idx0;   // pad with first valid
    __asm__ volatile("s_waitcnt lgkmcnt(0)" ::: "memory");  // LDS writes visible

    const float w0x = W[lane * 67 + 64], w0y = W[lane * 67 + 65], w0z = W[lane * 67 + 66];
    const float w1x = W[(lane + 64) * 67 + 64], w1y = W[(lane + 64) * 67 + 65], w1z = W[(lane + 64) * 67 + 66];
    const float b0 = bias[lane], b1 = bias[lane + 64];
    const float* Gb = G + (size_t)b * NN * OUTC;

    float acc = 0.f, mx = -3.4e38f;
    #pragma unroll 4
    for (int s = 0; s < NS; ++s) {
        int id = s_idx[w][s];
        const float* pr = xb + (size_t)id * 3;
        float dx = pr[0] - qx, dy = pr[1] - qy, dz = pr[2] - qz;
        const float* g = Gb + (size_t)id * OUTC;
        float y0 = g[lane]      + dx * w0x + dy * w0y + dz * w0z + b0;
        float y1 = g[lane + 64] + dx * w1x + dy * w1y + dz * w1z + b1;
        y0 = y0 > 0.f ? y0 : 0.01f * y0;
        y1 = y1 > 0.f ? y1 : 0.01f * y1;
        acc += y0;
        mx = fmaxf(mx, y1);
    }
    out0[(size_t)q * OUTC + lane]      = acc * (1.0f / 32.0f);
    out0[(size_t)q * OUTC + 64 + lane] = mx;
}

// ---------------------------------------------------------------------------
extern "C" void kernel_launch(void* const* d_in, const int* in_sizes, int n_in,
                              void* d_out, int out_size, void* d_ws, size_t ws_size,
                              hipStream_t stream)
{
    const float* feat  = (const float*)d_in[0];
    const float* xyz   = (const float*)d_in[1];
    const int*   mask  = (const int*)d_in[2];
    const int*   kmask = (const int*)d_in[3];
    const float* W     = (const float*)d_in[4];
    const float* bias  = (const float*)d_in[5];
    float* out = (float*)d_out;

    int*   fps_idx = (int*)d_ws;                          // 64 KB
    float* G       = (float*)((char*)d_ws + 65536);       // 32 MB

    // opt-in to >64KB dynamic LDS (host-side setting; graph-capture safe)
    hipFuncSetAttribute((const void*)fps_featw_kernel,
                        hipFuncAttributeMaxDynamicSharedMemorySize, FPS_LDS_BYTES);

    hipLaunchKernelGGL(fps_featw_kernel, dim3(BB + 32), dim3(FPS_T), FPS_LDS_BYTES, stream,
                       xyz, kmask, feat, W, fps_idx, G);
    hipLaunchKernelGGL(group_kernel, dim3(4096), dim3(256), 0, stream,
                       xyz, mask, kmask, W, bias, fps_idx, G, out);
}

// Round 8
// 1298.068 us; speedup vs baseline: 2.0104x; 1.3337x over previous
//
#include <hip/hip_runtime.h>

// Problem constants (fixed by the reference)
#define BB    8
#define NN    8192
#define MM    2048
#define CFEAT 64
#define OUTC  128
#define NS    32
#define NBUCK 128     // buckets per batch; bucket j owned by wave (j & 7)
#define FPS_T 512     // 8 waves

// ---------------------------------------------------------------------------
// DPP wave64 reductions (row_shr 1/2/4/8 + bcast15 + bcast31; lane63 holds the
// full reduction). bound_ctrl=false + old=self => shifted-out lanes = identity.
// ---------------------------------------------------------------------------
template<int C, int R>
__device__ __forceinline__ float dpp_maxf(float v) {
    int t = __builtin_amdgcn_update_dpp(__float_as_int(v), __float_as_int(v), C, R, 0xf, false);
    return fmaxf(v, __int_as_float(t));
}
template<int C, int R>
__device__ __forceinline__ float dpp_minf(float v) {
    int t = __builtin_amdgcn_update_dpp(__float_as_int(v), __float_as_int(v), C, R, 0xf, false);
    return fminf(v, __int_as_float(t));
}
template<int C, int R>
__device__ __forceinline__ unsigned long long dpp_maxu64(unsigned long long v) {
    unsigned lo = (unsigned)v, hi = (unsigned)(v >> 32);
    unsigned tlo = (unsigned)__builtin_amdgcn_update_dpp((int)lo, (int)lo, C, R, 0xf, false);
    unsigned thi = (unsigned)__builtin_amdgcn_update_dpp((int)hi, (int)hi, C, R, 0xf, false);
    unsigned long long t = ((unsigned long long)thi << 32) | tlo;
    return t > v ? t : v;
}
__device__ __forceinline__ float wred_maxf(float v) {
    v = dpp_maxf<0x111,0xf>(v); v = dpp_maxf<0x112,0xf>(v);
    v = dpp_maxf<0x114,0xf>(v); v = dpp_maxf<0x118,0xf>(v);
    v = dpp_maxf<0x142,0xa>(v); v = dpp_maxf<0x143,0xc>(v);
    return __int_as_float(__builtin_amdgcn_readlane(__float_as_int(v), 63));
}
__device__ __forceinline__ float wred_minf(float v) {
    v = dpp_minf<0x111,0xf>(v); v = dpp_minf<0x112,0xf>(v);
    v = dpp_minf<0x114,0xf>(v); v = dpp_minf<0x118,0xf>(v);
    v = dpp_minf<0x142,0xa>(v); v = dpp_minf<0x143,0xc>(v);
    return __int_as_float(__builtin_amdgcn_readlane(__float_as_int(v), 63));
}
// chain + explicit broadcast of lane63 -> all lanes
__device__ __forceinline__ unsigned long long wbcast_maxu64(unsigned long long v) {
    v = dpp_maxu64<0x111,0xf>(v); v = dpp_maxu64<0x112,0xf>(v);
    v = dpp_maxu64<0x114,0xf>(v); v = dpp_maxu64<0x118,0xf>(v);
    v = dpp_maxu64<0x142,0xa>(v); v = dpp_maxu64<0x143,0xc>(v);
    unsigned lo = (unsigned)__builtin_amdgcn_readlane((int)(unsigned)v, 63);
    unsigned hi = (unsigned)__builtin_amdgcn_readlane((int)(unsigned)(v >> 32), 63);
    return ((unsigned long long)hi << 32) | lo;
}

// identical fma shape for point distance and bbox lower bound => lb2 <= d2
// holds in f32 by per-op monotonicity (safe exact skipping).
__device__ __forceinline__ float distsq(float dx, float dy, float dz) {
    return fmaf(dz, dz, fmaf(dy, dy, dx * dx));
}

// key layout: (dmin_bits << 32) | ((8191-orig) << 13) | pos
// u64 max  =>  max dmin, ties -> min orig (orig unique => total order).
// Validated bit-exact in R5-R7 (passed correctness with this packing).
__device__ __forceinline__ unsigned long long pack_key(float dmn, unsigned orig, unsigned pos) {
    return ((unsigned long long)__float_as_uint(dmn) << 32)
         | ((unsigned long long)(8191u - orig) << 13) | pos;
}

// ---------------------------------------------------------------------------
// LDS layout (byte offsets), FPS path:
//   spt    [8192] float4 (x,y,z,dmin)       0   131072 B
//   sorig  [8192] u16               131072    16384 B
//   skey   [2][128] u64             147456     2048 B   (parity dbuf)
//   s_misc [4] i32                  149504       16 B
// total 149520 -> alloc 149760. bbox + own-bucket keys live in REGISTERS.
// ---------------------------------------------------------------------------
#define FPS_LDS_BYTES 149760

__global__ __launch_bounds__(FPS_T) void fps_featw_kernel(
    const float* __restrict__ xyz, const int* __restrict__ key_mask,
    const float* __restrict__ feat, const float* __restrict__ W,
    int* __restrict__ fps_idx, float* __restrict__ G)
{
    extern __shared__ float sm[];
    const int t    = threadIdx.x;
    const int lane = t & 63;
    const int w    = t >> 6;

    if (blockIdx.x >= BB) {
        // ------- featW path: 32 blocks x 8 waves x 256 pts -------
        float* Wt = sm;   // [c][o], 32 KB
        for (int i = t; i < CFEAT * OUTC; i += FPS_T) {
            int c = i >> 7, o = i & 127;
            Wt[i] = W[o * 67 + c];
        }
        __syncthreads();
        const int p0 = (blockIdx.x - BB) * 2048 + w * 256;
        for (int k = 0; k < 256; k += 2) {
            int pA = p0 + k, pB = pA + 1;
            float fa = feat[(size_t)pA * CFEAT + lane];
            float fb = feat[(size_t)pB * CFEAT + lane];
            float a0 = 0.f, a1 = 0.f, b0 = 0.f, b1 = 0.f;
            #pragma unroll 8
            for (int c = 0; c < CFEAT; ++c) {
                float ca = __shfl(fa, c), cb = __shfl(fb, c);
                float w0 = Wt[c * OUTC + lane], w1 = Wt[c * OUTC + 64 + lane];
                a0 = fmaf(ca, w0, a0); a1 = fmaf(ca, w1, a1);
                b0 = fmaf(cb, w0, b0); b1 = fmaf(cb, w1, b1);
            }
            G[(size_t)pA * OUTC + lane]      = a0;
            G[(size_t)pA * OUTC + 64 + lane] = a1;
            G[(size_t)pB * OUTC + lane]      = b0;
            G[(size_t)pB * OUTC + 64 + lane] = b1;
        }
        return;
    }

    // ------- FPS path -------
    float4*             spt   = (float4*)sm;                        // [8192]
    unsigned short*     sorig = (unsigned short*)((char*)sm + 131072);
    unsigned long long* skey  = (unsigned long long*)((char*)sm + 147456); // [2][128]
    int*                s_misc = (int*)((char*)sm + 149504);

    const int b = blockIdx.x;

    if (w == 0) {
        // pass A: count masked points (wave 0 only)
        int nm_total = 0;
        for (int c = 0; c < 128; ++c) {
            int km = key_mask[b * NN + c * 64 + lane];
            nm_total += (int)__popcll(__ballot(km != 0));
        }
        const int NU0 = NN - nm_total;
        if (lane == 0) *s_misc = NU0;

        // pass B: stable partition (unmasked by idx, then masked by idx) + scale
        int nu_seen = 0, nm_seen = 0;
        for (int c = 0; c < 128; ++c) {
            int orig = c * 64 + lane;
            const float* p = xyz + ((size_t)b * NN + orig) * 3;
            float x = p[0], y = p[1], z = p[2];
            int km = key_mask[b * NN + orig];
            float off = km ? ((float)orig + 10.0f) * 10.0f : 0.0f;  // exact
            unsigned long long bm = __ballot(km != 0);
            int below = (int)__popcll(bm & ((1ull << lane) - 1ull));
            int pos = km ? (NU0 + nm_seen + below) : (nu_seen + (lane - below));
            spt[pos] = make_float4(x + off, y + off, z + off, 1e10f);
            sorig[pos] = (unsigned short)orig;
            int cm = (int)__popcll(bm);
            nm_seen += cm; nu_seen += 64 - cm;
        }
    }
    __syncthreads();
    const int NU = *s_misc;

    // pass C: own buckets' bbox + initial key -> REGISTERS
    // lane L holds bucket ((L&15)<<3)|w  (replicated across the 4 lane groups)
    float rlox = 0.f, rloy = 0.f, rloz = 0.f, rhix = 0.f, rhiy = 0.f, rhiz = 0.f;
    unsigned long long rkey = 0;
    for (int i = 0; i < 16; ++i) {
        int j = (i << 3) | w;
        int p = (j << 6) + lane;
        float4 pt = spt[p];
        float lx = wred_minf(pt.x), hx = wred_maxf(pt.x);
        float ly = wred_minf(pt.y), hy = wred_maxf(pt.y);
        float lz = wred_minf(pt.z), hz = wred_maxf(pt.z);
        unsigned long long k = wbcast_maxu64(pack_key(1e10f, sorig[p], (unsigned)p));
        if ((lane & 15) == i) {
            rlox = lx; rhix = hx; rloy = ly; rhiy = hy; rloz = lz; rhiz = hz;
            rkey = k;
        }
    }

    // initial query = orig index 0
    int km0 = key_mask[b * NN];
    int pos0 = km0 ? NU : 0;
    float4 q0 = spt[pos0];
    float qx = q0.x, qy = q0.y, qz = q0.z;
    int s_last = 0;

    for (int it = 0; it < MM; ++it) {
        if (t == 0) fps_idx[b * MM + it] = s_last;

        // phase 1: skip tests, ALL-REGISTER (no LDS)
        float dmax = __uint_as_float((unsigned)(rkey >> 32));
        float dx = fmaxf(fmaxf(rlox - qx, qx - rhix), 0.f);
        float dy = fmaxf(fmaxf(rloy - qy, qy - rhiy), 0.f);
        float dz = fmaxf(fmaxf(rloz - qz, qz - rhiz), 0.f);
        float lb = distsq(dx, dy, dz);
        unsigned long long pend = __ballot(lb < dmax) & 0xFFFFull;

        // phase 2: update own pending buckets (cooperative 64-lane pass each)
        while (pend) {
            int i = __ffsll(pend) - 1; pend &= pend - 1;
            int jj = (i << 3) | w;
            int p = (jj << 6) + lane;
            float4 pt = spt[p];
            float d   = distsq(pt.x - qx, pt.y - qy, pt.z - qz);
            float dmn = fminf(pt.w, d);
            ((float*)(spt + p))[3] = dmn;        // write dmin (.w) only
            unsigned long long k = wbcast_maxu64(pack_key(dmn, sorig[p], (unsigned)p));
            if ((lane & 15) == i) rkey = k;
        }
        // dump own 16 keys (registers -> parity buffer; contiguous, no conflict)
        unsigned long long* kcur = skey + (it & 1) * NBUCK;
        if (lane < 16) kcur[w * 16 + lane] = rkey;
        __syncthreads();                         // the only barrier

        // phase 3: global argmax over 128 keys (2/lane), redundant per wave
        unsigned long long k0 = kcur[lane];
        unsigned long long k1 = kcur[lane + 64];
        unsigned long long kk = wbcast_maxu64(k0 > k1 ? k0 : k1);
        s_last = 8191 - (int)((kk >> 13) & 8191u);
        int pos = (int)(kk & 8191u);
        float4 qq = spt[pos];                    // uniform b128 (x,y,z used)
        qx = qq.x; qy = qq.y; qz = qq.z;
    }
}

// ---------------------------------------------------------------------------
// K3: fused ball query + gather + (G + gxyz*Wxyz + b) + LeakyReLU + pool.
// ---------------------------------------------------------------------------
__global__ __launch_bounds__(256) void group_kernel(
    const float* __restrict__ xyz, const int* __restrict__ mask,
    const int* __restrict__ key_mask, const float* __restrict__ W,
    const float* __restrict__ bias, const int* __restrict__ fps_idx,
    const float* __restrict__ G, float* __restrict__ out)
{
    __shared__ int s_idx[4][NS];
    const int t = threadIdx.x, lane = t & 63, w = t >> 6;
    const int q = blockIdx.x * 4 + w;         // 0..16383
    const int b = q >> 11;
    const int gi = fps_idx[q];

    const float* xb = xyz + (size_t)b * NN * 3;
    const float* qp = xb + (size_t)gi * 3;
    const float qx = qp[0], qy = qp[1], qz = qp[2];

    float* out0 = out;
    float* onx  = out  + (size_t)BB * MM * OUTC;
    float* onm  = onx  + (size_t)BB * MM * 3;
    float* onk  = onm  + (size_t)BB * MM;
    if (lane == 0) {
        onx[(size_t)q * 3 + 0] = qx;
        onx[(size_t)q * 3 + 1] = qy;
        onx[(size_t)q * 3 + 2] = qz;
        onm[q] = (float)mask[b * NN + gi];
        onk[q] = (float)key_mask[b * NN + gi];
    }

    const float q2 = qx * qx + qy * qy + qz * qz;
    int have = 0, idx0 = -1;
    for (int base = 0; base < NN; base += 64) {
        int n = base + lane;
        const float* p = xb + n * 3;
        float x = p[0], y = p[1], z = p[2];
        float p2 = x * x + y * y + z * z;
        float dt = qx * x + qy * y + qz * z;
        float d2 = (q2 + p2) - 2.0f * dt;
        bool within = d2 < 0.25f;
        unsigned long long bm = __ballot(within);
        if (bm) {
            if (idx0 < 0) idx0 = base + (__ffsll(bm) - 1);
            if (within) {
                int pos = have + __popcll(bm & ((1ull << lane) - 1ull));
                if (pos < NS) s_idx[w][pos] = n;
            }
            have += (int)__popcll(bm);
            if (have >= NS) break;
        }
    }
    if (have > NS) have = NS;
    if (lane >= have && lane < NS) s_idx[w][lane] = idx0;   // pad with first valid
    __asm__ volatile("s_waitcnt lgkmcnt(0)" ::: "memory");  // LDS writes visible

    const float w0x = W[lane * 67 + 64], w0y = W[lane * 67 + 65], w0z = W[lane * 67 + 66];
    const float w1x = W[(lane + 64) * 67 + 64], w1y = W[(lane + 64) * 67 + 65], w1z = W[(lane + 64) * 67 + 66];
    const float b0 = bias[lane], b1 = bias[lane + 64];
    const float* Gb = G + (size_t)b * NN * OUTC;

    float acc = 0.f, mx = -3.4e38f;
    #pragma unroll 4
    for (int s = 0; s < NS; ++s) {
        int id = s_idx[w][s];
        const float* pr = xb + (size_t)id * 3;
        float dx = pr[0] - qx, dy = pr[1] - qy, dz = pr[2] - qz;
        const float* g = Gb + (size_t)id * OUTC;
        float y0 = g[lane]      + dx * w0x + dy * w0y + dz * w0z + b0;
        float y1 = g[lane + 64] + dx * w1x + dy * w1y + dz * w1z + b1;
        y0 = y0 > 0.f ? y0 : 0.01f * y0;
        y1 = y1 > 0.f ? y1 : 0.01f * y1;
        acc += y0;
        mx = fmaxf(mx, y1);
    }
    out0[(size_t)q * OUTC + lane]      = acc * (1.0f / 32.0f);
    out0[(size_t)q * OUTC + 64 + lane] = mx;
}

// ---------------------------------------------------------------------------
extern "C" void kernel_launch(void* const* d_in, const int* in_sizes, int n_in,
                              void* d_out, int out_size, void* d_ws, size_t ws_size,
                              hipStream_t stream)
{
    const float* feat  = (const float*)d_in[0];
    const float* xyz   = (const float*)d_in[1];
    const int*   mask  = (const int*)d_in[2];
    const int*   kmask = (const int*)d_in[3];
    const float* W     = (const float*)d_in[4];
    const float* bias  = (const float*)d_in[5];
    float* out = (float*)d_out;

    int*   fps_idx = (int*)d_ws;                          // 64 KB
    float* G       = (float*)((char*)d_ws + 65536);       // 32 MB

    // opt-in to >64KB dynamic LDS (host-side setting; graph-capture safe)
    hipFuncSetAttribute((const void*)fps_featw_kernel,
                        hipFuncAttributeMaxDynamicSharedMemorySize, FPS_LDS_BYTES);

    hipLaunchKernelGGL(fps_featw_kernel, dim3(BB + 32), dim3(FPS_T), FPS_LDS_BYTES, stream,
                       xyz, kmask, feat, W, fps_idx, G);
    hipLaunchKernelGGL(group_kernel, dim3(4096), dim3(256), 0, stream,
                       xyz, mask, kmask, W, bias, fps_idx, G, out);
}